// Round 6
// baseline (191.661 us; speedup 1.0000x reference)
//
#include <hip/hip_runtime.h>

// FusedMHC: per 8x8 block, M = exp(x), then 5 Sinkhorn-Knopp iterations.
// 4 threads per matrix; each thread owns 2 rows (16 floats) in registers.
//
// BARRIER-FREE version: all LDS traffic is wave-private.
//   Wave w (of 4 in the block) owns float4 slots [256w, 256w+256):
//   - stage-in/out passes use g = w*256 + p*64 + lane (64-consecutive, coalesced)
//   - gather/scatter touch matrices m = t>>2 in [16w, 16w+16) -> same region
//   - XOR swizzle s = g ^ ((g>>4)&15) permutes only the low nibble, so it
//     stays in-region. DS ops are wave-wide -> a wave-local
//     s_waitcnt lgkmcnt(0) makes cross-lane LDS writes visible.
//   => zero __syncthreads, no vmcnt(0) block drains, waves free-run and the
//      memory pipe is kept busy by TLP (32 waves/CU, wave-cap occupancy).
//
// Sinkhorn via scale factors (out = M0 * r_i * c_j; M0 untouched):
//   r_i = 1/sum_j M0[i][j]*c_j ; c_j = 1/sum_i M0[i][j]*r_i, c init 1.
// Col sums via DPP quad_perm butterfly (no DS pipe).

constexpr int MHC_ITERS = 5;
constexpr int THREADS = 256;
constexpr int MATS_PER_BLOCK = THREADS / 4;        // 64 matrices/block
constexpr int F4_PER_BLOCK = MATS_PER_BLOCK * 16;  // 1024 float4 = 16 KB

// dpp_ctrl must be a compile-time constant -> template parameter.
template <int CTRL>
__device__ __forceinline__ float quad_xor_add(float x) {
    int peer = __builtin_amdgcn_update_dpp(0, __float_as_int(x), CTRL, 0xF, 0xF, true);
    return x + __int_as_float(peer);
}

// Wave-local LDS fence: all of this wave's DS ops complete (all 64 lanes of a
// DS instruction finish together; LDS has no caches). "memory" clobber keeps
// the compiler from moving LDS accesses across it.
__device__ __forceinline__ void lds_fence() {
    asm volatile("s_waitcnt lgkmcnt(0)" ::: "memory");
}

__global__ __launch_bounds__(THREADS)
void fused_mhc_kernel(const float* __restrict__ x, float* __restrict__ out) {
    __shared__ float4 lds[F4_PER_BLOCK];

    const int t = threadIdx.x;
    const int lane = t & 63;
    const int w = t >> 6;  // wave id within block
    const size_t base = (size_t)blockIdx.x * F4_PER_BLOCK;
    const float4* __restrict__ src = reinterpret_cast<const float4*>(x) + base;
    float4* __restrict__ dst = reinterpret_cast<float4*>(out) + base;

    // ---- Stage in (wave-local): coalesced global -> swizzled LDS ----
    #pragma unroll
    for (int p = 0; p < 4; ++p) {
        int g = w * 256 + p * 64 + lane;
        lds[g ^ ((g >> 4) & 15)] = src[g];
    }
    lds_fence();  // cross-lane (same-wave) ds_writes visible before gather

    // ---- Gather: thread (m,h) owns rows 2h, 2h+1 of local matrix m ----
    const int m = t >> 2;   // in [16w, 16w+16) -> wave-private region
    const int h = t & 3;
    const int swz = m & 15;

    float M[16];  // M[0..7] = row 2h, M[8..15] = row 2h+1
    #pragma unroll
    for (int j = 0; j < 4; ++j) {
        float4 v = lds[(m * 16 + h * 4 + j) ^ swz];
        M[j * 4 + 0] = v.x;
        M[j * 4 + 1] = v.y;
        M[j * 4 + 2] = v.z;
        M[j * 4 + 3] = v.w;
    }

    #pragma unroll
    for (int i = 0; i < 16; ++i) M[i] = __expf(M[i]);

    // ---- Sinkhorn via row/col scale factors; M stays untouched ----
    float c[8];
    #pragma unroll
    for (int j = 0; j < 8; ++j) c[j] = 1.0f;

    float r0, r1;
    #pragma unroll
    for (int it = 0; it < MHC_ITERS; ++it) {
        // Row phase: r_i = 1 / sum_j M[i][j]*c_j (thread-local).
        float d0 = M[0] * c[0];
        float d1 = M[8] * c[0];
        #pragma unroll
        for (int j = 1; j < 8; ++j) {
            d0 = fmaf(M[j], c[j], d0);
            d1 = fmaf(M[8 + j], c[j], d1);
        }
        r0 = __builtin_amdgcn_rcpf(d0);
        r1 = __builtin_amdgcn_rcpf(d1);

        // Col phase: c_j = 1 / sum_i M[i][j]*r_i (DPP quad butterfly).
        // 0xB1 = quad_perm [1,0,3,2] (xor 1), 0x4E = quad_perm [2,3,0,1] (xor 2).
        #pragma unroll
        for (int j = 0; j < 8; ++j) {
            float p = fmaf(M[8 + j], r1, M[j] * r0);
            p = quad_xor_add<0xB1>(p);
            p = quad_xor_add<0x4E>(p);
            c[j] = __builtin_amdgcn_rcpf(p);
        }
    }

    // ---- Apply scales, scatter to own swizzled slots (wave-private) ----
    #pragma unroll
    for (int j = 0; j < 8; ++j) {
        M[j] *= r0 * c[j];
        M[8 + j] *= r1 * c[j];
    }

    #pragma unroll
    for (int j = 0; j < 4; ++j) {
        float4 v;
        v.x = M[j * 4 + 0];
        v.y = M[j * 4 + 1];
        v.z = M[j * 4 + 2];
        v.w = M[j * 4 + 3];
        lds[(m * 16 + h * 4 + j) ^ swz] = v;
    }
    lds_fence();  // cross-lane scatter visible before stage-out reads

    // ---- Stage out (wave-local): swizzled LDS -> coalesced global ----
    #pragma unroll
    for (int p = 0; p < 4; ++p) {
        int g = w * 256 + p * 64 + lane;
        dst[g] = lds[g ^ ((g >> 4) & 15)];
    }
}

extern "C" void kernel_launch(void* const* d_in, const int* in_sizes, int n_in,
                              void* d_out, int out_size, void* d_ws, size_t ws_size,
                              hipStream_t stream) {
    const float* x = (const float*)d_in[0];
    float* out = (float*)d_out;

    const int nmat = in_sizes[0] / 64;                // 8x8 matrices
    const int blocks = nmat / MATS_PER_BLOCK;         // 2,097,152 / 64 = 32768

    fused_mhc_kernel<<<blocks, THREADS, 0, stream>>>(x, out);
}

// Round 7
// 176.639 us; speedup vs baseline: 1.0850x; 1.0850x over previous
//
#include <hip/hip_runtime.h>

// FusedMHC: per 8x8 block, M = exp(x), then 5 Sinkhorn-Knopp iterations.
// 4 threads per matrix; each thread owns 2 rows (16 floats) in registers.
//
// R7 change: NONTEMPORAL load/store on the global streams (nt bit).
// Both streams are stream-once (input never re-read, output never read), so
// default L1/L2/L3 allocation is pure churn: 1 GB through 4 MiB/XCD L2.
// nt -> evict-first / minimal allocation, writes drain closer to the
// write-only fill kernel's 6.5-6.8 TB/s.
//
// Structure (unchanged from R6, barrier-free):
// - Wave-private LDS staging regions, XOR swizzle s = g ^ ((g>>4)&15)
//   (involution; stage passes conflict-free, gather/scatter <=2-way).
// - Wave-local s_waitcnt lgkmcnt(0) instead of __syncthreads.
// - Sinkhorn via scale factors (M0 untouched): r_i = 1/sum_j M0[i][j]*c_j,
//   c_j = 1/sum_i M0[i][j]*r_i; col sums via DPP quad_perm butterfly.
// - 64 B LDS/thread -> wave-cap occupancy: 8 blocks/CU, 32 waves/CU.

constexpr int MHC_ITERS = 5;
constexpr int THREADS = 256;
constexpr int MATS_PER_BLOCK = THREADS / 4;        // 64 matrices/block
constexpr int F4_PER_BLOCK = MATS_PER_BLOCK * 16;  // 1024 float4 = 16 KB

typedef float f32x4 __attribute__((ext_vector_type(4)));

// dpp_ctrl must be a compile-time constant -> template parameter.
template <int CTRL>
__device__ __forceinline__ float quad_xor_add(float x) {
    int peer = __builtin_amdgcn_update_dpp(0, __float_as_int(x), CTRL, 0xF, 0xF, true);
    return x + __int_as_float(peer);
}

// Wave-local LDS fence: this wave's DS ops complete; "memory" clobber stops
// the compiler from reordering LDS accesses across it.
__device__ __forceinline__ void lds_fence() {
    asm volatile("s_waitcnt lgkmcnt(0)" ::: "memory");
}

__global__ __launch_bounds__(THREADS)
void fused_mhc_kernel(const float* __restrict__ x, float* __restrict__ out) {
    __shared__ f32x4 lds[F4_PER_BLOCK];

    const int t = threadIdx.x;
    const int lane = t & 63;
    const int w = t >> 6;  // wave id within block
    const size_t base = (size_t)blockIdx.x * F4_PER_BLOCK;
    const f32x4* __restrict__ src = reinterpret_cast<const f32x4*>(x) + base;
    f32x4* __restrict__ dst = reinterpret_cast<f32x4*>(out) + base;

    // ---- Stage in (wave-local): nt global -> swizzled LDS ----
    #pragma unroll
    for (int p = 0; p < 4; ++p) {
        int g = w * 256 + p * 64 + lane;
        lds[g ^ ((g >> 4) & 15)] = __builtin_nontemporal_load(&src[g]);
    }
    lds_fence();  // cross-lane (same-wave) ds_writes visible before gather

    // ---- Gather: thread (m,h) owns rows 2h, 2h+1 of local matrix m ----
    const int m = t >> 2;   // in [16w, 16w+16) -> wave-private region
    const int h = t & 3;
    const int swz = m & 15;

    float M[16];  // M[0..7] = row 2h, M[8..15] = row 2h+1
    #pragma unroll
    for (int j = 0; j < 4; ++j) {
        f32x4 v = lds[(m * 16 + h * 4 + j) ^ swz];
        M[j * 4 + 0] = v.x;
        M[j * 4 + 1] = v.y;
        M[j * 4 + 2] = v.z;
        M[j * 4 + 3] = v.w;
    }

    #pragma unroll
    for (int i = 0; i < 16; ++i) M[i] = __expf(M[i]);

    // ---- Sinkhorn via row/col scale factors; M stays untouched ----
    float c[8];
    #pragma unroll
    for (int j = 0; j < 8; ++j) c[j] = 1.0f;

    float r0, r1;
    #pragma unroll
    for (int it = 0; it < MHC_ITERS; ++it) {
        // Row phase: r_i = 1 / sum_j M[i][j]*c_j (thread-local).
        float d0 = M[0] * c[0];
        float d1 = M[8] * c[0];
        #pragma unroll
        for (int j = 1; j < 8; ++j) {
            d0 = fmaf(M[j], c[j], d0);
            d1 = fmaf(M[8 + j], c[j], d1);
        }
        r0 = __builtin_amdgcn_rcpf(d0);
        r1 = __builtin_amdgcn_rcpf(d1);

        // Col phase: c_j = 1 / sum_i M[i][j]*r_i (DPP quad butterfly).
        // 0xB1 = quad_perm [1,0,3,2] (xor 1), 0x4E = quad_perm [2,3,0,1] (xor 2).
        #pragma unroll
        for (int j = 0; j < 8; ++j) {
            float p = fmaf(M[8 + j], r1, M[j] * r0);
            p = quad_xor_add<0xB1>(p);
            p = quad_xor_add<0x4E>(p);
            c[j] = __builtin_amdgcn_rcpf(p);
        }
    }

    // ---- Apply scales, scatter to own swizzled slots (wave-private) ----
    #pragma unroll
    for (int j = 0; j < 8; ++j) {
        M[j] *= r0 * c[j];
        M[8 + j] *= r1 * c[j];
    }

    #pragma unroll
    for (int j = 0; j < 4; ++j) {
        f32x4 v;
        v.x = M[j * 4 + 0];
        v.y = M[j * 4 + 1];
        v.z = M[j * 4 + 2];
        v.w = M[j * 4 + 3];
        lds[(m * 16 + h * 4 + j) ^ swz] = v;
    }
    lds_fence();  // cross-lane scatter visible before stage-out reads

    // ---- Stage out (wave-local): swizzled LDS -> nt global ----
    #pragma unroll
    for (int p = 0; p < 4; ++p) {
        int g = w * 256 + p * 64 + lane;
        __builtin_nontemporal_store(lds[g ^ ((g >> 4) & 15)], &dst[g]);
    }
}

extern "C" void kernel_launch(void* const* d_in, const int* in_sizes, int n_in,
                              void* d_out, int out_size, void* d_ws, size_t ws_size,
                              hipStream_t stream) {
    const float* x = (const float*)d_in[0];
    float* out = (float*)d_out;

    const int nmat = in_sizes[0] / 64;                // 8x8 matrices
    const int blocks = nmat / MATS_PER_BLOCK;         // 2,097,152 / 64 = 32768

    fused_mhc_kernel<<<blocks, THREADS, 0, stream>>>(x, out);
}